// Round 5
// baseline (1449.997 us; speedup 1.0000x reference)
//
#include <hip/hip_runtime.h>
#include <cstdint>

#define BN_EPS 1e-5f

typedef unsigned int uint;

// ---------------------------------------------------------------------------
// x:  (32, 256, 28, 28) f32
// w1: (1024, 256, 3, 3)  conv1: 256 -> 1024 (groups collapse: same input)
// w2: (1024, 256, 3, 3)  conv2: grouped x4
// out: (32, 256, 28, 28) f32
// Packing: 256 ch -> 8 u32 words; bit (c%32) of word (c/32) = (v>=0)
// Weights packed [tap][1024 oc][8 words] so lane-consecutive oc reads are
// 32B-strided (coalesced) instead of 288B-strided.
//
// Column decomposition: out(x) = q0(col x-1) + q1(col x) + q2(col x+1).
// Both convs process 2 y-rows per block to amortize weight regs + LDS fill.
// ---------------------------------------------------------------------------

__global__ __launch_bounds__(256) void kPrep(
    const float* __restrict__ s1, const float* __restrict__ b1,
    const float* __restrict__ m1, const float* __restrict__ v1,
    const float* __restrict__ s2, const float* __restrict__ b2,
    const float* __restrict__ m2, const float* __restrict__ v2,
    const float* __restrict__ lam,
    float* __restrict__ bnA1, float* __restrict__ bnB1,
    float* __restrict__ bnA2, float* __restrict__ bnB2) {
  int t = blockIdx.x * 256 + threadIdx.x;
  if (t >= 1024) return;
  float inv1 = s1[t] / sqrtf(v1[t] + BN_EPS);
  bnA1[t] = inv1;
  bnB1[t] = b1[t] - m1[t] * inv1;
  float inv2 = s2[t] / sqrtf(v2[t] + BN_EPS);
  float l = lam[t >> 8];
  bnA2[t] = inv2 * l;
  bnB2[t] = (b2[t] - m2[t] * inv2) * l;
}

// Each lane reads one full 64B line (16 consecutive px of its channel),
// then 16 ballots pack channel bits.
__global__ __launch_bounds__(256) void kPackX(const float* __restrict__ x,
                                              uint* __restrict__ A1p) {
  const int tid = threadIdx.x;
  const int lane = tid & 63, cb = tid >> 6;
  const int grp = blockIdx.x;  // 0..1567 = 32 b * 49 groups of 16 px
  const int b = grp / 49, r16 = (grp % 49) * 16;
  const float4* src = (const float4*)(x + ((b * 256 + cb * 64 + lane) * 784 + r16));
  float4 f0 = src[0], f1 = src[1], f2 = src[2], f3 = src[3];
  uint* outp = A1p + (b * 784 + r16) * 8 + cb * 2;
#define PB(V, PX) { unsigned long long m = __ballot((V) >= 0.0f); \
    if (lane == 0) { outp[(PX)*8] = (uint)m; outp[(PX)*8+1] = (uint)(m>>32); } }
  PB(f0.x, 0)  PB(f0.y, 1)  PB(f0.z, 2)  PB(f0.w, 3)
  PB(f1.x, 4)  PB(f1.y, 5)  PB(f1.z, 6)  PB(f1.w, 7)
  PB(f2.x, 8)  PB(f2.y, 9)  PB(f2.z, 10) PB(f2.w, 11)
  PB(f3.x, 12) PB(f3.y, 13) PB(f3.z, 14) PB(f3.w, 15)
#undef PB
}

// Pack weight sign bits, layout [tap][1024 oc][8 words]
__global__ __launch_bounds__(256) void kPackW(const float* __restrict__ w,
                                              uint* __restrict__ Wp) {
  int wg = blockIdx.x * 4 + (threadIdx.x >> 6);
  int lane = threadIdx.x & 63;
  int oc = wg / 36;
  int r = wg - oc * 36;
  int tap = r >> 2;
  int cb = r & 3;
  float v = w[(oc * 256 + cb * 64 + lane) * 9 + tap];
  unsigned long long m = __ballot(v >= 0.0f);
  if (lane == 0) {
    Wp[(tap * 1024 + oc) * 8 + cb * 2]     = (uint)m;
    Wp[(tap * 1024 + oc) * 8 + cb * 2 + 1] = (uint)(m >> 32);
  }
}

// ---------------- conv1: padded LDS + columns + 2 y-rows -------------------
// block = 256 (4 waves = oc chunks); grid (4 quad, 14 ytile, 32 b)

#define XP8(A0, A1, WP) (__popc((A0).x ^ (WP)[0]) + __popc((A0).y ^ (WP)[1]) + \
                         __popc((A0).z ^ (WP)[2]) + __popc((A0).w ^ (WP)[3]) + \
                         __popc((A1).x ^ (WP)[4]) + __popc((A1).y ^ (WP)[5]) + \
                         __popc((A1).z ^ (WP)[6]) + __popc((A1).w ^ (WP)[7]))

#define COL1(P, D0, D1, D2, EMIT, X, THR) { \
  const uint4* ap = abase + (P) * 2; \
  int q0 = 0, q1 = 0, q2 = 0; \
  { uint4 ra = ap[0],   rb = ap[1]; \
    if (D0) q0 += XP8(ra, rb, wr + 0);  if (D1) q1 += XP8(ra, rb, wr + 8); \
    if (D2) q2 += XP8(ra, rb, wr + 16); } \
  { uint4 ra = ap[60],  rb = ap[61]; \
    if (D0) q0 += XP8(ra, rb, wr + 24); if (D1) q1 += XP8(ra, rb, wr + 32); \
    if (D2) q2 += XP8(ra, rb, wr + 40); } \
  { uint4 ra = ap[120], rb = ap[121]; \
    if (D0) q0 += XP8(ra, rb, wr + 48); if (D1) q1 += XP8(ra, rb, wr + 56); \
    if (D2) q2 += XP8(ra, rb, wr + 64); } \
  if (EMIT) { int Sx = a0 + q2; \
    unsigned long long m = __ballot((float)Sx < (THR)); \
    if (lane == 0) { outp[(X) * 32] = (uint)m; outp[(X) * 32 + 1] = (uint)(m >> 32); } } \
  a0 = a1 + q1; a1 = q0; }

__global__ __launch_bounds__(256) void kConv1(
    const uint* __restrict__ A1p, const uint* __restrict__ W1p,
    const float* __restrict__ bnA1, const float* __restrict__ bnB1,
    uint* __restrict__ A2p) {
  const int tid = threadIdx.x;
  const int lane = tid & 63;
  const int quad = blockIdx.x, ytile = blockIdx.y, b = blockIdx.z;
  const int y0 = ytile * 2;
  const int chunk = quad * 4 + (tid >> 6);
  const int oc = chunk * 64 + lane;

  __shared__ uint apad[960];  // [4 rows][30 cols][8 words], zero padded
  { uint4* z = (uint4*)apad;
    if (tid < 240) z[tid] = make_uint4(0u, 0u, 0u, 0u); }
  __syncthreads();
  if (tid < 224) {  // 4 rows x 56 uint4
    int r = tid / 56, idx = tid - r * 56;
    int ry = y0 - 1 + r;
    if (ry >= 0 && ry < 28) {
      ((uint4*)apad)[r * 60 + 2 + idx] =
          ((const uint4*)(A1p + (b * 784 + ry * 28) * 8))[idx];
    }
  }
  __syncthreads();

  uint wr[72];
#pragma unroll
  for (int t = 0; t < 9; t++) {
    const uint4* wsrc = ((const uint4*)W1p) + (t * 1024 + oc) * 2;
    uint4 w0 = wsrc[0], w1 = wsrc[1];
    wr[t*8+0] = w0.x; wr[t*8+1] = w0.y; wr[t*8+2] = w0.z; wr[t*8+3] = w0.w;
    wr[t*8+4] = w1.x; wr[t*8+5] = w1.y; wr[t*8+6] = w1.z; wr[t*8+7] = w1.w;
  }
  int pw[9];
#pragma unroll
  for (int t9 = 0; t9 < 9; t9++) {
    int s = 0;
#pragma unroll
    for (int i = 0; i < 8; i++) s += __popc(wr[t9*8 + i]);
    pw[t9] = s;
  }
  const float inv = bnA1[oc], bb = bnB1[oc];
  const float tneg = -bb / inv;  // bn1_scale >= 0 -> inv >= 0

  for (int yy = 0; yy < 2; yy++) {
    const int y = y0 + yy;
    const int ytop = (y > 0) ? 1 : 0, ybot = (y < 27) ? 1 : 0;
    const int nrv = 1 + ytop + ybot;
    int pwInvRow = 0;
    if (!ytop) pwInvRow += pw[0] + pw[1] + pw[2];
    if (!ybot) pwInvRow += pw[6] + pw[7] + pw[8];
    int pwV0 = pw[3], pwV2 = pw[5];
    if (ytop) { pwV0 += pw[0]; pwV2 += pw[2]; }
    if (ybot) { pwV0 += pw[6]; pwV2 += pw[8]; }
    const float thrM  = ((float)(256 * 3 * nrv + 2 * pwInvRow) - tneg) * 0.5f;
    const float thr0  = ((float)(256 * 2 * nrv + 2 * (pwInvRow + pwV0)) - tneg) * 0.5f;
    const float thr27 = ((float)(256 * 2 * nrv + 2 * (pwInvRow + pwV2)) - tneg) * 0.5f;

    uint* outp = A2p + (b * 784 + y * 28) * 32 + chunk * 2;
    const uint4* abase = ((const uint4*)apad) + yy * 60;
    int a0 = 0, a1 = 0;
    COL1(0, 1, 0, 0, 0, 0, 0.0f)
    COL1(1, 1, 1, 0, 0, 0, 0.0f)
    COL1(2, 1, 1, 1, 1, 0, thr0)
    for (int p = 3; p <= 24; p += 3) {  // rolled: cols 3..26, emits x=1..24
      COL1(p,     1, 1, 1, 1, (p - 2), thrM)
      COL1(p + 1, 1, 1, 1, 1, (p - 1), thrM)
      COL1(p + 2, 1, 1, 1, 1, (p),     thrM)
    }
    COL1(27, 1, 1, 1, 1, 25, thrM)
    COL1(28, 0, 1, 1, 1, 26, thrM)
    COL1(29, 0, 0, 1, 1, 27, thr27)
  }
}

// Per-(pixel,group) popcount of A2
__global__ __launch_bounds__(256) void kS(const uint* __restrict__ A2p,
                                          uint* __restrict__ S) {
  int idx = blockIdx.x * 256 + threadIdx.x;
  if (idx >= 25088 * 4) return;
  int pix = idx >> 2, g = idx & 3;
  const uint* p = A2p + pix * 32 + g * 8;
  int t = 0;
#pragma unroll
  for (int w = 0; w < 8; w++) t += __popc(p[w]);
  S[idx] = (uint)t;
}

// 3x3 zero-padded box sum of S -> float
__global__ __launch_bounds__(256) void kBS(const uint* __restrict__ S,
                                           float* __restrict__ BSf) {
  int idx = blockIdx.x * 256 + threadIdx.x;
  if (idx >= 25088 * 4) return;
  int pix = idx >> 2, g = idx & 3;
  int b = pix / 784, rem = pix - b * 784;
  int y = rem / 28, x = rem - y * 28;
  int t = 0;
  for (int dy = -1; dy <= 1; dy++) {
    int ry = y + dy;
    if (ry < 0 || ry >= 28) continue;
    for (int dx = -1; dx <= 1; dx++) {
      int rx = x + dx;
      if (rx < 0 || rx >= 28) continue;
      t += (int)S[((b * 784 + ry * 28 + rx) << 2) + g];
    }
  }
  BSf[idx] = (float)t;
}

// ---------------- conv2: 2 y-rows x 2 x-halves, padded LDS, columns --------
// block 256 = 4 waves; wave = (ysub, xhalf): 14 outputs/thread, lane = c;
// grid (4 cchunk, 14 ytile, 32 b).

#define AP8(A0, A1, WP) (__popc((A0).x & (WP)[0]) + __popc((A0).y & (WP)[1]) + \
                         __popc((A0).z & (WP)[2]) + __popc((A0).w & (WP)[3]) + \
                         __popc((A1).x & (WP)[4]) + __popc((A1).y & (WP)[5]) + \
                         __popc((A1).z & (WP)[6]) + __popc((A1).w & (WP)[7]))

#define COL2(K, D0, D1, D2, EMIT, XI) { \
  const uint4* ap = abase + (s + (K)) * 8 + g * 2; \
  int q0 = 0, q1 = 0, q2 = 0; \
  { uint4 ra = ap[0],   rb = ap[1]; \
    if (D0) q0 += AP8(ra, rb, wr + 0);  if (D1) q1 += AP8(ra, rb, wr + 8); \
    if (D2) q2 += AP8(ra, rb, wr + 16); } \
  { uint4 ra = ap[240], rb = ap[241]; \
    if (D0) q0 += AP8(ra, rb, wr + 24); if (D1) q1 += AP8(ra, rb, wr + 32); \
    if (D2) q2 += AP8(ra, rb, wr + 40); } \
  { uint4 ra = ap[480], rb = ap[481]; \
    if (D0) q0 += AP8(ra, rb, wr + 48); if (D1) q1 += AP8(ra, rb, wr + 56); \
    if (D2) q2 += AP8(ra, rb, wr + 64); } \
  if (EMIT) { int Sx = a0 + q2; \
    float bs = bsl[(s + (XI)) * 4 + g]; \
    val[XI] += fmaf((float)Sx, inv2, fmaf(-inv, bs, bb)); } \
  a0 = a1 + q1; a1 = q0; }

__global__ __launch_bounds__(256, 4) void kConv2(
    const uint* __restrict__ A2p, const uint* __restrict__ W2p,
    const float* __restrict__ BSf,
    const float* __restrict__ bnA2, const float* __restrict__ bnB2,
    const float* __restrict__ xin, float* __restrict__ out) {
  const int tid = threadIdx.x;
  const int lane = tid & 63;
  const int ysub = tid >> 7, xh = (tid >> 6) & 1;
  const int cchunk = blockIdx.x, ytile = blockIdx.y, b = blockIdx.z;
  const int y0 = ytile * 2, y = y0 + ysub;
  const int s = xh * 14;

  __shared__ uint apad[3840];     // [4 rows][30 cols][32 words], zero padded
  __shared__ float bsrow[2][112]; // per y row: [28 x][4 g]

  { uint4* z = (uint4*)apad;
    for (int i = tid; i < 960; i += 256) z[i] = make_uint4(0u, 0u, 0u, 0u); }
  if (tid < 224) {
    int yrow = tid / 112, j = tid - yrow * 112;
    bsrow[yrow][j] = BSf[(b * 784 + (y0 + yrow) * 28) * 4 + j];
  }
  __syncthreads();
  {  // fill 4 rows x 224 uint4
    for (int i = tid; i < 896; i += 256) {
      int r = i >> 5 >> 3;          // i / 256? no: r = i/224
      r = i / 224; int c = i - r * 224;
      int ry = y0 - 1 + r;
      if (ry >= 0 && ry < 28) {
        int col = c >> 3, h = c & 7;
        ((uint4*)apad)[r * 240 + (col + 1) * 8 + h] =
            ((const uint4*)(A2p + (b * 784 + ry * 28) * 32))[c];
      }
    }
  }
  __syncthreads();

  float val[14];
#pragma unroll
  for (int i = 0; i < 14; i++) val[i] = 0.0f;

  const uint4* abase = ((const uint4*)apad) + ysub * 240;
  const float* bsl = &bsrow[ysub][0];

  for (int g = 0; g < 4; g++) {
    const int oc = g * 256 + cchunk * 64 + lane;
    uint wr[72];
#pragma unroll
    for (int t = 0; t < 9; t++) {
      const uint4* wsrc = ((const uint4*)W2p) + (t * 1024 + oc) * 2;
      uint4 w0 = wsrc[0], w1 = wsrc[1];
      wr[t*8+0] = w0.x; wr[t*8+1] = w0.y; wr[t*8+2] = w0.z; wr[t*8+3] = w0.w;
      wr[t*8+4] = w1.x; wr[t*8+5] = w1.y; wr[t*8+6] = w1.z; wr[t*8+7] = w1.w;
    }
    const float inv = bnA2[oc], bb = bnB2[oc];
    const float inv2 = 2.0f * inv;
    int a0 = 0, a1 = 0;
    COL2(0,  1, 0, 0, 0, 0)
    COL2(1,  1, 1, 0, 0, 0)
    COL2(2,  1, 1, 1, 1, 0)
    COL2(3,  1, 1, 1, 1, 1)
    COL2(4,  1, 1, 1, 1, 2)
    COL2(5,  1, 1, 1, 1, 3)
    COL2(6,  1, 1, 1, 1, 4)
    COL2(7,  1, 1, 1, 1, 5)
    COL2(8,  1, 1, 1, 1, 6)
    COL2(9,  1, 1, 1, 1, 7)
    COL2(10, 1, 1, 1, 1, 8)
    COL2(11, 1, 1, 1, 1, 9)
    COL2(12, 1, 1, 1, 1, 10)
    COL2(13, 1, 1, 1, 1, 11)
    COL2(14, 0, 1, 1, 1, 12)
    COL2(15, 0, 0, 1, 1, 13)
  }

  const int c = cchunk * 64 + lane;
  const int obase = ((b * 256 + c) * 28 + y) * 28;
#pragma unroll
  for (int xi = 0; xi < 14; xi++) {
    int x = s + xi;
    float o = val[xi] + xin[obase + x];
    out[obase + x] = fmaxf(o, 0.0f);
  }
}

extern "C" void kernel_launch(void* const* d_in, const int* in_sizes, int n_in,
                              void* d_out, int out_size, void* d_ws, size_t ws_size,
                              hipStream_t stream) {
  const float* x   = (const float*)d_in[0];
  const float* w1  = (const float*)d_in[1];
  const float* s1  = (const float*)d_in[2];
  const float* b1  = (const float*)d_in[3];
  const float* m1  = (const float*)d_in[4];
  const float* v1  = (const float*)d_in[5];
  const float* w2  = (const float*)d_in[6];
  const float* s2  = (const float*)d_in[7];
  const float* b2  = (const float*)d_in[8];
  const float* m2  = (const float*)d_in[9];
  const float* v2  = (const float*)d_in[10];
  const float* lam = (const float*)d_in[11];
  float* out = (float*)d_out;

  char* ws = (char*)d_ws;
  uint*  A1p  = (uint*)(ws + 0);          //   802816 B
  uint*  W1p  = (uint*)(ws + 802816);     //   294912 B
  uint*  W2p  = (uint*)(ws + 1097728);    //   294912 B
  uint*  A2p  = (uint*)(ws + 1392640);    //  3211264 B
  uint*  Sb   = (uint*)(ws + 4603904);    //   401408 B
  float* BSf  = (float*)(ws + 5005312);   //   401408 B
  float* bnA1 = (float*)(ws + 5406720);
  float* bnB1 = (float*)(ws + 5410816);
  float* bnA2 = (float*)(ws + 5414912);
  float* bnB2 = (float*)(ws + 5419008);

  kPrep<<<4, 256, 0, stream>>>(s1, b1, m1, v1, s2, b2, m2, v2, lam,
                               bnA1, bnB1, bnA2, bnB2);
  kPackX<<<1568, 256, 0, stream>>>(x, A1p);
  kPackW<<<9216, 256, 0, stream>>>(w1, W1p);
  kPackW<<<9216, 256, 0, stream>>>(w2, W2p);
  kConv1<<<dim3(4, 14, 32), 256, 0, stream>>>(A1p, W1p, bnA1, bnB1, A2p);
  kS<<<(25088 * 4 + 255) / 256, 256, 0, stream>>>(A2p, Sb);
  kBS<<<(25088 * 4 + 255) / 256, 256, 0, stream>>>(Sb, BSf);
  kConv2<<<dim3(4, 14, 32), 256, 0, stream>>>(A2p, W2p, BSf, bnA2, bnB2, x, out);
}

// Round 6
// 369.149 us; speedup vs baseline: 3.9279x; 3.9279x over previous
//
#include <hip/hip_runtime.h>
#include <cstdint>

#define BN_EPS 1e-5f

typedef unsigned int uint;

// ---------------------------------------------------------------------------
// x:  (32, 256, 28, 28) f32
// w1: (1024, 256, 3, 3)  conv1: 256 -> 1024 (groups collapse: same input)
// w2: (1024, 256, 3, 3)  conv2: grouped x4
// out: (32, 256, 28, 28) f32
// Packing: 256 ch -> 8 u32 words; bit (c%32) of word (c/32) = (v>=0)
// Weights packed [tap][1024 oc][8 words] (coalesced: lane stride 32B).
//
// Column decomposition: out(x) = q0(col x-1) + q1(col x) + q2(col x+1).
// Both convs process 2 y-rows per block to amortize weight regs + LDS fill.
// NOTE: no min-waves arg on __launch_bounds__ — (256,4) means 4 waves/SIMD
// on CDNA and capped VGPR at 64 -> wr[72]+val[14] spilled -> 6.3 GB scratch
// traffic, 1285us (r5). Unconstrained alloc (~150 VGPR) is correct here.
// ---------------------------------------------------------------------------

__global__ __launch_bounds__(256) void kPrep(
    const float* __restrict__ s1, const float* __restrict__ b1,
    const float* __restrict__ m1, const float* __restrict__ v1,
    const float* __restrict__ s2, const float* __restrict__ b2,
    const float* __restrict__ m2, const float* __restrict__ v2,
    const float* __restrict__ lam,
    float* __restrict__ bnA1, float* __restrict__ bnB1,
    float* __restrict__ bnA2, float* __restrict__ bnB2) {
  int t = blockIdx.x * 256 + threadIdx.x;
  if (t >= 1024) return;
  float inv1 = s1[t] / sqrtf(v1[t] + BN_EPS);
  bnA1[t] = inv1;
  bnB1[t] = b1[t] - m1[t] * inv1;
  float inv2 = s2[t] / sqrtf(v2[t] + BN_EPS);
  float l = lam[t >> 8];
  bnA2[t] = inv2 * l;
  bnB2[t] = (b2[t] - m2[t] * inv2) * l;
}

// Each lane reads one full 64B line (16 consecutive px of its channel),
// then 16 ballots pack channel bits.
__global__ __launch_bounds__(256) void kPackX(const float* __restrict__ x,
                                              uint* __restrict__ A1p) {
  const int tid = threadIdx.x;
  const int lane = tid & 63, cb = tid >> 6;
  const int grp = blockIdx.x;  // 0..1567 = 32 b * 49 groups of 16 px
  const int b = grp / 49, r16 = (grp % 49) * 16;
  const float4* src = (const float4*)(x + ((b * 256 + cb * 64 + lane) * 784 + r16));
  float4 f0 = src[0], f1 = src[1], f2 = src[2], f3 = src[3];
  uint* outp = A1p + (b * 784 + r16) * 8 + cb * 2;
#define PB(V, PX) { unsigned long long m = __ballot((V) >= 0.0f); \
    if (lane == 0) { outp[(PX)*8] = (uint)m; outp[(PX)*8+1] = (uint)(m>>32); } }
  PB(f0.x, 0)  PB(f0.y, 1)  PB(f0.z, 2)  PB(f0.w, 3)
  PB(f1.x, 4)  PB(f1.y, 5)  PB(f1.z, 6)  PB(f1.w, 7)
  PB(f2.x, 8)  PB(f2.y, 9)  PB(f2.z, 10) PB(f2.w, 11)
  PB(f3.x, 12) PB(f3.y, 13) PB(f3.z, 14) PB(f3.w, 15)
#undef PB
}

// Pack weight sign bits, layout [tap][1024 oc][8 words]
__global__ __launch_bounds__(256) void kPackW(const float* __restrict__ w,
                                              uint* __restrict__ Wp) {
  int wg = blockIdx.x * 4 + (threadIdx.x >> 6);
  int lane = threadIdx.x & 63;
  int oc = wg / 36;
  int r = wg - oc * 36;
  int tap = r >> 2;
  int cb = r & 3;
  float v = w[(oc * 256 + cb * 64 + lane) * 9 + tap];
  unsigned long long m = __ballot(v >= 0.0f);
  if (lane == 0) {
    Wp[(tap * 1024 + oc) * 8 + cb * 2]     = (uint)m;
    Wp[(tap * 1024 + oc) * 8 + cb * 2 + 1] = (uint)(m >> 32);
  }
}

// ---------------- conv1: padded LDS + columns + 2 y-rows -------------------
// block = 256 (4 waves = oc chunks); grid (4 quad, 14 ytile, 32 b)

#define XP8(A0, A1, WP) (__popc((A0).x ^ (WP)[0]) + __popc((A0).y ^ (WP)[1]) + \
                         __popc((A0).z ^ (WP)[2]) + __popc((A0).w ^ (WP)[3]) + \
                         __popc((A1).x ^ (WP)[4]) + __popc((A1).y ^ (WP)[5]) + \
                         __popc((A1).z ^ (WP)[6]) + __popc((A1).w ^ (WP)[7]))

#define COL1(P, D0, D1, D2, EMIT, X, THR) { \
  const uint4* ap = abase + (P) * 2; \
  int q0 = 0, q1 = 0, q2 = 0; \
  { uint4 ra = ap[0],   rb = ap[1]; \
    if (D0) q0 += XP8(ra, rb, wr + 0);  if (D1) q1 += XP8(ra, rb, wr + 8); \
    if (D2) q2 += XP8(ra, rb, wr + 16); } \
  { uint4 ra = ap[60],  rb = ap[61]; \
    if (D0) q0 += XP8(ra, rb, wr + 24); if (D1) q1 += XP8(ra, rb, wr + 32); \
    if (D2) q2 += XP8(ra, rb, wr + 40); } \
  { uint4 ra = ap[120], rb = ap[121]; \
    if (D0) q0 += XP8(ra, rb, wr + 48); if (D1) q1 += XP8(ra, rb, wr + 56); \
    if (D2) q2 += XP8(ra, rb, wr + 64); } \
  if (EMIT) { int Sx = a0 + q2; \
    unsigned long long m = __ballot((float)Sx < (THR)); \
    if (lane == 0) { outp[(X) * 32] = (uint)m; outp[(X) * 32 + 1] = (uint)(m >> 32); } } \
  a0 = a1 + q1; a1 = q0; }

__global__ __launch_bounds__(256) void kConv1(
    const uint* __restrict__ A1p, const uint* __restrict__ W1p,
    const float* __restrict__ bnA1, const float* __restrict__ bnB1,
    uint* __restrict__ A2p) {
  const int tid = threadIdx.x;
  const int lane = tid & 63;
  const int quad = blockIdx.x, ytile = blockIdx.y, b = blockIdx.z;
  const int y0 = ytile * 2;
  const int chunk = quad * 4 + (tid >> 6);
  const int oc = chunk * 64 + lane;

  __shared__ uint apad[960];  // [4 rows][30 cols][8 words], zero padded
  { uint4* z = (uint4*)apad;
    if (tid < 240) z[tid] = make_uint4(0u, 0u, 0u, 0u); }
  __syncthreads();
  if (tid < 224) {  // 4 rows x 56 uint4
    int r = tid / 56, idx = tid - r * 56;
    int ry = y0 - 1 + r;
    if (ry >= 0 && ry < 28) {
      ((uint4*)apad)[r * 60 + 2 + idx] =
          ((const uint4*)(A1p + (b * 784 + ry * 28) * 8))[idx];
    }
  }
  __syncthreads();

  uint wr[72];
#pragma unroll
  for (int t = 0; t < 9; t++) {
    const uint4* wsrc = ((const uint4*)W1p) + (t * 1024 + oc) * 2;
    uint4 w0 = wsrc[0], w1 = wsrc[1];
    wr[t*8+0] = w0.x; wr[t*8+1] = w0.y; wr[t*8+2] = w0.z; wr[t*8+3] = w0.w;
    wr[t*8+4] = w1.x; wr[t*8+5] = w1.y; wr[t*8+6] = w1.z; wr[t*8+7] = w1.w;
  }
  int pw[9];
#pragma unroll
  for (int t9 = 0; t9 < 9; t9++) {
    int s = 0;
#pragma unroll
    for (int i = 0; i < 8; i++) s += __popc(wr[t9*8 + i]);
    pw[t9] = s;
  }
  const float inv = bnA1[oc], bb = bnB1[oc];
  const float tneg = -bb / inv;  // bn1_scale >= 0 -> inv >= 0

  for (int yy = 0; yy < 2; yy++) {
    const int y = y0 + yy;
    const int ytop = (y > 0) ? 1 : 0, ybot = (y < 27) ? 1 : 0;
    const int nrv = 1 + ytop + ybot;
    int pwInvRow = 0;
    if (!ytop) pwInvRow += pw[0] + pw[1] + pw[2];
    if (!ybot) pwInvRow += pw[6] + pw[7] + pw[8];
    int pwV0 = pw[3], pwV2 = pw[5];
    if (ytop) { pwV0 += pw[0]; pwV2 += pw[2]; }
    if (ybot) { pwV0 += pw[6]; pwV2 += pw[8]; }
    const float thrM  = ((float)(256 * 3 * nrv + 2 * pwInvRow) - tneg) * 0.5f;
    const float thr0  = ((float)(256 * 2 * nrv + 2 * (pwInvRow + pwV0)) - tneg) * 0.5f;
    const float thr27 = ((float)(256 * 2 * nrv + 2 * (pwInvRow + pwV2)) - tneg) * 0.5f;

    uint* outp = A2p + (b * 784 + y * 28) * 32 + chunk * 2;
    const uint4* abase = ((const uint4*)apad) + yy * 60;
    int a0 = 0, a1 = 0;
    COL1(0, 1, 0, 0, 0, 0, 0.0f)
    COL1(1, 1, 1, 0, 0, 0, 0.0f)
    COL1(2, 1, 1, 1, 1, 0, thr0)
    for (int p = 3; p <= 24; p += 3) {  // rolled: cols 3..26, emits x=1..24
      COL1(p,     1, 1, 1, 1, (p - 2), thrM)
      COL1(p + 1, 1, 1, 1, 1, (p - 1), thrM)
      COL1(p + 2, 1, 1, 1, 1, (p),     thrM)
    }
    COL1(27, 1, 1, 1, 1, 25, thrM)
    COL1(28, 0, 1, 1, 1, 26, thrM)
    COL1(29, 0, 0, 1, 1, 27, thr27)
  }
}

// Per-(pixel,group) popcount of A2
__global__ __launch_bounds__(256) void kS(const uint* __restrict__ A2p,
                                          uint* __restrict__ S) {
  int idx = blockIdx.x * 256 + threadIdx.x;
  if (idx >= 25088 * 4) return;
  int pix = idx >> 2, g = idx & 3;
  const uint* p = A2p + pix * 32 + g * 8;
  int t = 0;
#pragma unroll
  for (int w = 0; w < 8; w++) t += __popc(p[w]);
  S[idx] = (uint)t;
}

// 3x3 zero-padded box sum of S -> float
__global__ __launch_bounds__(256) void kBS(const uint* __restrict__ S,
                                           float* __restrict__ BSf) {
  int idx = blockIdx.x * 256 + threadIdx.x;
  if (idx >= 25088 * 4) return;
  int pix = idx >> 2, g = idx & 3;
  int b = pix / 784, rem = pix - b * 784;
  int y = rem / 28, x = rem - y * 28;
  int t = 0;
  for (int dy = -1; dy <= 1; dy++) {
    int ry = y + dy;
    if (ry < 0 || ry >= 28) continue;
    for (int dx = -1; dx <= 1; dx++) {
      int rx = x + dx;
      if (rx < 0 || rx >= 28) continue;
      t += (int)S[((b * 784 + ry * 28 + rx) << 2) + g];
    }
  }
  BSf[idx] = (float)t;
}

// ---------------- conv2: 2 y-rows x 2 x-halves, padded LDS, columns --------
// block 256 = 4 waves; wave = (ysub, xhalf): 14 outputs/thread, lane = c;
// grid (4 cchunk, 14 ytile, 32 b).

#define AP8(A0, A1, WP) (__popc((A0).x & (WP)[0]) + __popc((A0).y & (WP)[1]) + \
                         __popc((A0).z & (WP)[2]) + __popc((A0).w & (WP)[3]) + \
                         __popc((A1).x & (WP)[4]) + __popc((A1).y & (WP)[5]) + \
                         __popc((A1).z & (WP)[6]) + __popc((A1).w & (WP)[7]))

#define COL2(K, D0, D1, D2, EMIT, XI) { \
  const uint4* ap = abase + (s + (K)) * 8 + g * 2; \
  int q0 = 0, q1 = 0, q2 = 0; \
  { uint4 ra = ap[0],   rb = ap[1]; \
    if (D0) q0 += AP8(ra, rb, wr + 0);  if (D1) q1 += AP8(ra, rb, wr + 8); \
    if (D2) q2 += AP8(ra, rb, wr + 16); } \
  { uint4 ra = ap[240], rb = ap[241]; \
    if (D0) q0 += AP8(ra, rb, wr + 24); if (D1) q1 += AP8(ra, rb, wr + 32); \
    if (D2) q2 += AP8(ra, rb, wr + 40); } \
  { uint4 ra = ap[480], rb = ap[481]; \
    if (D0) q0 += AP8(ra, rb, wr + 48); if (D1) q1 += AP8(ra, rb, wr + 56); \
    if (D2) q2 += AP8(ra, rb, wr + 64); } \
  if (EMIT) { int Sx = a0 + q2; \
    float bs = bsl[(s + (XI)) * 4 + g]; \
    val[XI] += fmaf((float)Sx, inv2, fmaf(-inv, bs, bb)); } \
  a0 = a1 + q1; a1 = q0; }

__global__ __launch_bounds__(256) void kConv2(
    const uint* __restrict__ A2p, const uint* __restrict__ W2p,
    const float* __restrict__ BSf,
    const float* __restrict__ bnA2, const float* __restrict__ bnB2,
    const float* __restrict__ xin, float* __restrict__ out) {
  const int tid = threadIdx.x;
  const int lane = tid & 63;
  const int ysub = tid >> 7, xh = (tid >> 6) & 1;
  const int cchunk = blockIdx.x, ytile = blockIdx.y, b = blockIdx.z;
  const int y0 = ytile * 2, y = y0 + ysub;
  const int s = xh * 14;

  __shared__ uint apad[3840];     // [4 rows][30 cols][32 words], zero padded
  __shared__ float bsrow[2][112]; // per y row: [28 x][4 g]

  { uint4* z = (uint4*)apad;
    for (int i = tid; i < 960; i += 256) z[i] = make_uint4(0u, 0u, 0u, 0u); }
  if (tid < 224) {
    int yrow = tid / 112, j = tid - yrow * 112;
    bsrow[yrow][j] = BSf[(b * 784 + (y0 + yrow) * 28) * 4 + j];
  }
  __syncthreads();
  for (int i = tid; i < 896; i += 256) {  // 4 rows x 224 uint4
    int r = i / 224, c = i - r * 224;
    int ry = y0 - 1 + r;
    if (ry >= 0 && ry < 28) {
      int col = c >> 3, h = c & 7;
      ((uint4*)apad)[r * 240 + (col + 1) * 8 + h] =
          ((const uint4*)(A2p + (b * 784 + ry * 28) * 32))[c];
    }
  }
  __syncthreads();

  float val[14];
#pragma unroll
  for (int i = 0; i < 14; i++) val[i] = 0.0f;

  const uint4* abase = ((const uint4*)apad) + ysub * 240;
  const float* bsl = &bsrow[ysub][0];

  for (int g = 0; g < 4; g++) {
    const int oc = g * 256 + cchunk * 64 + lane;
    uint wr[72];
#pragma unroll
    for (int t = 0; t < 9; t++) {
      const uint4* wsrc = ((const uint4*)W2p) + (t * 1024 + oc) * 2;
      uint4 w0 = wsrc[0], w1 = wsrc[1];
      wr[t*8+0] = w0.x; wr[t*8+1] = w0.y; wr[t*8+2] = w0.z; wr[t*8+3] = w0.w;
      wr[t*8+4] = w1.x; wr[t*8+5] = w1.y; wr[t*8+6] = w1.z; wr[t*8+7] = w1.w;
    }
    const float inv = bnA2[oc], bb = bnB2[oc];
    const float inv2 = 2.0f * inv;
    int a0 = 0, a1 = 0;
    COL2(0,  1, 0, 0, 0, 0)
    COL2(1,  1, 1, 0, 0, 0)
    COL2(2,  1, 1, 1, 1, 0)
    COL2(3,  1, 1, 1, 1, 1)
    COL2(4,  1, 1, 1, 1, 2)
    COL2(5,  1, 1, 1, 1, 3)
    COL2(6,  1, 1, 1, 1, 4)
    COL2(7,  1, 1, 1, 1, 5)
    COL2(8,  1, 1, 1, 1, 6)
    COL2(9,  1, 1, 1, 1, 7)
    COL2(10, 1, 1, 1, 1, 8)
    COL2(11, 1, 1, 1, 1, 9)
    COL2(12, 1, 1, 1, 1, 10)
    COL2(13, 1, 1, 1, 1, 11)
    COL2(14, 0, 1, 1, 1, 12)
    COL2(15, 0, 0, 1, 1, 13)
  }

  const int c = cchunk * 64 + lane;
  const int obase = ((b * 256 + c) * 28 + y) * 28;
#pragma unroll
  for (int xi = 0; xi < 14; xi++) {
    int x = s + xi;
    float o = val[xi] + xin[obase + x];
    out[obase + x] = fmaxf(o, 0.0f);
  }
}

extern "C" void kernel_launch(void* const* d_in, const int* in_sizes, int n_in,
                              void* d_out, int out_size, void* d_ws, size_t ws_size,
                              hipStream_t stream) {
  const float* x   = (const float*)d_in[0];
  const float* w1  = (const float*)d_in[1];
  const float* s1  = (const float*)d_in[2];
  const float* b1  = (const float*)d_in[3];
  const float* m1  = (const float*)d_in[4];
  const float* v1  = (const float*)d_in[5];
  const float* w2  = (const float*)d_in[6];
  const float* s2  = (const float*)d_in[7];
  const float* b2  = (const float*)d_in[8];
  const float* m2  = (const float*)d_in[9];
  const float* v2  = (const float*)d_in[10];
  const float* lam = (const float*)d_in[11];
  float* out = (float*)d_out;

  char* ws = (char*)d_ws;
  uint*  A1p  = (uint*)(ws + 0);          //   802816 B
  uint*  W1p  = (uint*)(ws + 802816);     //   294912 B
  uint*  W2p  = (uint*)(ws + 1097728);    //   294912 B
  uint*  A2p  = (uint*)(ws + 1392640);    //  3211264 B
  uint*  Sb   = (uint*)(ws + 4603904);    //   401408 B
  float* BSf  = (float*)(ws + 5005312);   //   401408 B
  float* bnA1 = (float*)(ws + 5406720);
  float* bnB1 = (float*)(ws + 5410816);
  float* bnA2 = (float*)(ws + 5414912);
  float* bnB2 = (float*)(ws + 5419008);

  kPrep<<<4, 256, 0, stream>>>(s1, b1, m1, v1, s2, b2, m2, v2, lam,
                               bnA1, bnB1, bnA2, bnB2);
  kPackX<<<1568, 256, 0, stream>>>(x, A1p);
  kPackW<<<9216, 256, 0, stream>>>(w1, W1p);
  kPackW<<<9216, 256, 0, stream>>>(w2, W2p);
  kConv1<<<dim3(4, 14, 32), 256, 0, stream>>>(A1p, W1p, bnA1, bnB1, A2p);
  kS<<<(25088 * 4 + 255) / 256, 256, 0, stream>>>(A2p, Sb);
  kBS<<<(25088 * 4 + 255) / 256, 256, 0, stream>>>(Sb, BSf);
  kConv2<<<dim3(4, 14, 32), 256, 0, stream>>>(A2p, W2p, BSf, bnA2, bnB2, x, out);
}

// Round 7
// 307.822 us; speedup vs baseline: 4.7105x; 1.1992x over previous
//
#include <hip/hip_runtime.h>
#include <cstdint>

#define BN_EPS 1e-5f

typedef unsigned int uint;

// ---------------------------------------------------------------------------
// x:  (32, 256, 28, 28) f32
// w1: (1024, 256, 3, 3)  conv1: 256 -> 1024 (groups collapse: same input)
// w2: (1024, 256, 3, 3)  conv2: grouped x4
// out: (32, 256, 28, 28) f32
// Packing: 256 ch -> 8 u32 words; bit (c%32) of word (c/32) = (v>=0)
// Weights packed [half][tap][1024 oc][4 words]: one lane-coalesced 16B load
// gives 4 words (128 ic) of one tap.
//
// kConv2 r7 restructure: per g, loop halves (128 ic each) holding only
// wr[36] live -> VGPR ~80 (was 140 at wr[72]) -> occupancy + LDS prefetch
// headroom. Bias/box-sum term moved to epilogue; kS+kBS fused into the
// kConv2 prologue (computed in-LDS from the apad tile).
// NOTE (r5): __launch_bounds__ 2nd arg is waves/SIMD on CDNA; (256,4)
// capped VGPR at 64 and spilled 6.3 GB. Leave it unconstrained.
// ---------------------------------------------------------------------------

__global__ __launch_bounds__(256) void kPrep(
    const float* __restrict__ s1, const float* __restrict__ b1,
    const float* __restrict__ m1, const float* __restrict__ v1,
    const float* __restrict__ s2, const float* __restrict__ b2,
    const float* __restrict__ m2, const float* __restrict__ v2,
    const float* __restrict__ lam,
    float* __restrict__ bnA1, float* __restrict__ bnB1,
    float* __restrict__ bnA2, float* __restrict__ bnB2) {
  int t = blockIdx.x * 256 + threadIdx.x;
  if (t >= 1024) return;
  float inv1 = s1[t] / sqrtf(v1[t] + BN_EPS);
  bnA1[t] = inv1;
  bnB1[t] = b1[t] - m1[t] * inv1;
  float inv2 = s2[t] / sqrtf(v2[t] + BN_EPS);
  float l = lam[t >> 8];
  bnA2[t] = inv2 * l;
  bnB2[t] = (b2[t] - m2[t] * inv2) * l;
}

// Each lane reads one full 64B line (16 consecutive px of its channel),
// then 16 ballots pack channel bits.
__global__ __launch_bounds__(256) void kPackX(const float* __restrict__ x,
                                              uint* __restrict__ A1p) {
  const int tid = threadIdx.x;
  const int lane = tid & 63, cb = tid >> 6;
  const int grp = blockIdx.x;  // 0..1567 = 32 b * 49 groups of 16 px
  const int b = grp / 49, r16 = (grp % 49) * 16;
  const float4* src = (const float4*)(x + ((b * 256 + cb * 64 + lane) * 784 + r16));
  float4 f0 = src[0], f1 = src[1], f2 = src[2], f3 = src[3];
  uint* outp = A1p + (b * 784 + r16) * 8 + cb * 2;
#define PB(V, PX) { unsigned long long m = __ballot((V) >= 0.0f); \
    if (lane == 0) { outp[(PX)*8] = (uint)m; outp[(PX)*8+1] = (uint)(m>>32); } }
  PB(f0.x, 0)  PB(f0.y, 1)  PB(f0.z, 2)  PB(f0.w, 3)
  PB(f1.x, 4)  PB(f1.y, 5)  PB(f1.z, 6)  PB(f1.w, 7)
  PB(f2.x, 8)  PB(f2.y, 9)  PB(f2.z, 10) PB(f2.w, 11)
  PB(f3.x, 12) PB(f3.y, 13) PB(f3.z, 14) PB(f3.w, 15)
#undef PB
}

// Pack weight sign bits, layout [half][tap][1024 oc][4 words]
__global__ __launch_bounds__(256) void kPackW(const float* __restrict__ w,
                                              uint* __restrict__ Wp) {
  int wg = blockIdx.x * 4 + (threadIdx.x >> 6);
  int lane = threadIdx.x & 63;
  int oc = wg / 36;
  int r = wg - oc * 36;
  int tap = r >> 2;
  int cb = r & 3;  // 64-ch block; half = cb>>1, words (cb&1)*2, +1
  float v = w[(oc * 256 + cb * 64 + lane) * 9 + tap];
  unsigned long long m = __ballot(v >= 0.0f);
  if (lane == 0) {
    uint* dst = Wp + (((cb >> 1) * 9 + tap) * 1024 + oc) * 4 + (cb & 1) * 2;
    dst[0] = (uint)m;
    dst[1] = (uint)(m >> 32);
  }
}

// ---------------- conv1: padded LDS + columns + 2 y-rows (r6 config) -------
// block = 256 (4 waves = oc chunks); grid (4 quad, 14 ytile, 32 b)

#define XP8(A0, A1, WP) (__popc((A0).x ^ (WP)[0]) + __popc((A0).y ^ (WP)[1]) + \
                         __popc((A0).z ^ (WP)[2]) + __popc((A0).w ^ (WP)[3]) + \
                         __popc((A1).x ^ (WP)[4]) + __popc((A1).y ^ (WP)[5]) + \
                         __popc((A1).z ^ (WP)[6]) + __popc((A1).w ^ (WP)[7]))

#define COL1(P, D0, D1, D2, EMIT, X, THR) { \
  const uint4* ap = abase + (P) * 2; \
  int q0 = 0, q1 = 0, q2 = 0; \
  { uint4 ra = ap[0],   rb = ap[1]; \
    if (D0) q0 += XP8(ra, rb, wr + 0);  if (D1) q1 += XP8(ra, rb, wr + 8); \
    if (D2) q2 += XP8(ra, rb, wr + 16); } \
  { uint4 ra = ap[60],  rb = ap[61]; \
    if (D0) q0 += XP8(ra, rb, wr + 24); if (D1) q1 += XP8(ra, rb, wr + 32); \
    if (D2) q2 += XP8(ra, rb, wr + 40); } \
  { uint4 ra = ap[120], rb = ap[121]; \
    if (D0) q0 += XP8(ra, rb, wr + 48); if (D1) q1 += XP8(ra, rb, wr + 56); \
    if (D2) q2 += XP8(ra, rb, wr + 64); } \
  if (EMIT) { int Sx = a0 + q2; \
    unsigned long long m = __ballot((float)Sx < (THR)); \
    if (lane == 0) { outp[(X) * 32] = (uint)m; outp[(X) * 32 + 1] = (uint)(m >> 32); } } \
  a0 = a1 + q1; a1 = q0; }

__global__ __launch_bounds__(256) void kConv1(
    const uint* __restrict__ A1p, const uint* __restrict__ W1p,
    const float* __restrict__ bnA1, const float* __restrict__ bnB1,
    uint* __restrict__ A2p) {
  const int tid = threadIdx.x;
  const int lane = tid & 63;
  const int quad = blockIdx.x, ytile = blockIdx.y, b = blockIdx.z;
  const int y0 = ytile * 2;
  const int chunk = quad * 4 + (tid >> 6);
  const int oc = chunk * 64 + lane;

  __shared__ uint apad[960];  // [4 rows][30 cols][8 words], zero padded
  { uint4* z = (uint4*)apad;
    if (tid < 240) z[tid] = make_uint4(0u, 0u, 0u, 0u); }
  __syncthreads();
  if (tid < 224) {  // 4 rows x 56 uint4
    int r = tid / 56, idx = tid - r * 56;
    int ry = y0 - 1 + r;
    if (ry >= 0 && ry < 28) {
      ((uint4*)apad)[r * 60 + 2 + idx] =
          ((const uint4*)(A1p + (b * 784 + ry * 28) * 8))[idx];
    }
  }
  __syncthreads();

  uint wr[72];
  const uint4* wb = ((const uint4*)W1p) + oc;
#pragma unroll
  for (int t = 0; t < 9; t++) {
    uint4 w0 = wb[t * 1024];         // half0: (0*9+t)*1024+oc
    uint4 w1 = wb[(9 + t) * 1024];   // half1
    wr[t*8+0] = w0.x; wr[t*8+1] = w0.y; wr[t*8+2] = w0.z; wr[t*8+3] = w0.w;
    wr[t*8+4] = w1.x; wr[t*8+5] = w1.y; wr[t*8+6] = w1.z; wr[t*8+7] = w1.w;
  }
  int pw[9];
#pragma unroll
  for (int t9 = 0; t9 < 9; t9++) {
    int s = 0;
#pragma unroll
    for (int i = 0; i < 8; i++) s += __popc(wr[t9*8 + i]);
    pw[t9] = s;
  }
  const float inv = bnA1[oc], bb = bnB1[oc];
  const float tneg = -bb / inv;  // bn1_scale >= 0 -> inv >= 0

  for (int yy = 0; yy < 2; yy++) {
    const int y = y0 + yy;
    const int ytop = (y > 0) ? 1 : 0, ybot = (y < 27) ? 1 : 0;
    const int nrv = 1 + ytop + ybot;
    int pwInvRow = 0;
    if (!ytop) pwInvRow += pw[0] + pw[1] + pw[2];
    if (!ybot) pwInvRow += pw[6] + pw[7] + pw[8];
    int pwV0 = pw[3], pwV2 = pw[5];
    if (ytop) { pwV0 += pw[0]; pwV2 += pw[2]; }
    if (ybot) { pwV0 += pw[6]; pwV2 += pw[8]; }
    const float thrM  = ((float)(256 * 3 * nrv + 2 * pwInvRow) - tneg) * 0.5f;
    const float thr0  = ((float)(256 * 2 * nrv + 2 * (pwInvRow + pwV0)) - tneg) * 0.5f;
    const float thr27 = ((float)(256 * 2 * nrv + 2 * (pwInvRow + pwV2)) - tneg) * 0.5f;

    uint* outp = A2p + (b * 784 + y * 28) * 32 + chunk * 2;
    const uint4* abase = ((const uint4*)apad) + yy * 60;
    int a0 = 0, a1 = 0;
    COL1(0, 1, 0, 0, 0, 0, 0.0f)
    COL1(1, 1, 1, 0, 0, 0, 0.0f)
    COL1(2, 1, 1, 1, 1, 0, thr0)
    for (int p = 3; p <= 24; p += 3) {  // rolled: cols 3..26, emits x=1..24
      COL1(p,     1, 1, 1, 1, (p - 2), thrM)
      COL1(p + 1, 1, 1, 1, 1, (p - 1), thrM)
      COL1(p + 2, 1, 1, 1, 1, (p),     thrM)
    }
    COL1(27, 1, 1, 1, 1, 25, thrM)
    COL1(28, 0, 1, 1, 1, 26, thrM)
    COL1(29, 0, 0, 1, 1, 27, thr27)
  }
}

// ---------------- conv2: half-split weights, fused S/box-sum ---------------
// block 256 = 4 waves; wave = (ysub, xhalf): 14 outputs/thread, lane = c;
// grid (4 cchunk, 14 ytile, 32 b). Per g: 2 half-passes with wr[36] live.

#define AP4(A, WP) (__popc((A).x & (WP)[0]) + __popc((A).y & (WP)[1]) + \
                    __popc((A).z & (WP)[2]) + __popc((A).w & (WP)[3]))

#define COL2(K, D0, D1, D2, EMIT, XI) { \
  const uint4* ap = abase + (s + (K)) * 8 + g * 2 + h; \
  int q0 = 0, q1 = 0, q2 = 0; \
  { uint4 ra = ap[0]; \
    if (D0) q0 += AP4(ra, wr + 0);  if (D1) q1 += AP4(ra, wr + 4); \
    if (D2) q2 += AP4(ra, wr + 8); } \
  { uint4 ra = ap[240]; \
    if (D0) q0 += AP4(ra, wr + 12); if (D1) q1 += AP4(ra, wr + 16); \
    if (D2) q2 += AP4(ra, wr + 20); } \
  { uint4 ra = ap[480]; \
    if (D0) q0 += AP4(ra, wr + 24); if (D1) q1 += AP4(ra, wr + 28); \
    if (D2) q2 += AP4(ra, wr + 32); } \
  if (EMIT) { int Sx = a0 + q2; val[XI] += (float)Sx * inv2; } \
  a0 = a1 + q1; a1 = q0; }

__global__ __launch_bounds__(256) void kConv2(
    const uint* __restrict__ A2p, const uint* __restrict__ W2p,
    const float* __restrict__ bnA2, const float* __restrict__ bnB2,
    const float* __restrict__ xin, float* __restrict__ out) {
  const int tid = threadIdx.x;
  const int lane = tid & 63;
  const int ysub = tid >> 7, xh = (tid >> 6) & 1;
  const int cchunk = blockIdx.x, ytile = blockIdx.y, b = blockIdx.z;
  const int y0 = ytile * 2, y = y0 + ysub;
  const int s = xh * 14;

  __shared__ uint apad[3840];      // [4 rows][30 cols][32 words], zero padded
  __shared__ int sp[4][30][4];     // per-(row,col,g) popcount of apad
  __shared__ float bsrow[2][28][4];// per y row: 3x3 box sum

  { uint4* z = (uint4*)apad;
    for (int i = tid; i < 960; i += 256) z[i] = make_uint4(0u, 0u, 0u, 0u); }
  __syncthreads();
  for (int i = tid; i < 896; i += 256) {  // 4 rows x 224 uint4
    int r = i / 224, c = i - r * 224;
    int ry = y0 - 1 + r;
    if (ry >= 0 && ry < 28) {
      int col = c >> 3, hh = c & 7;
      ((uint4*)apad)[r * 240 + (col + 1) * 8 + hh] =
          ((const uint4*)(A2p + (b * 784 + ry * 28) * 32))[c];
    }
  }
  __syncthreads();
  // S per (row, col, g) from the resident tile (replaces kS kernel)
  for (int e = tid; e < 480; e += 256) {
    int r = e / 120, rem = e - r * 120;
    int c = rem >> 2, g2 = rem & 3;
    const uint4* p = ((const uint4*)apad) + (r * 30 + c) * 8 + g2 * 2;
    uint4 A = p[0], B = p[1];
    sp[r][c][g2] = __popc(A.x) + __popc(A.y) + __popc(A.z) + __popc(A.w) +
                   __popc(B.x) + __popc(B.y) + __popc(B.z) + __popc(B.w);
  }
  __syncthreads();
  // 3x3 box sums (replaces kBS kernel); apad zero-padding makes edges correct
  for (int e = tid; e < 224; e += 256) {
    int yy = e / 112, rem = e - yy * 112;
    int xx = rem >> 2, g2 = rem & 3;
    int t = sp[yy][xx][g2]     + sp[yy][xx+1][g2]     + sp[yy][xx+2][g2]
          + sp[yy+1][xx][g2]   + sp[yy+1][xx+1][g2]   + sp[yy+1][xx+2][g2]
          + sp[yy+2][xx][g2]   + sp[yy+2][xx+1][g2]   + sp[yy+2][xx+2][g2];
    bsrow[yy][xx][g2] = (float)t;
  }
  __syncthreads();

  float val[14];
#pragma unroll
  for (int i = 0; i < 14; i++) val[i] = 0.0f;

  const uint4* abase = ((const uint4*)apad) + ysub * 240;

#pragma unroll 1
  for (int g = 0; g < 4; g++) {
    const int oc = g * 256 + cchunk * 64 + lane;
    const float inv2 = 2.0f * bnA2[oc];
#pragma unroll 1
    for (int h = 0; h < 2; h++) {
      uint wr[36];
      const uint4* wbase = ((const uint4*)W2p) + (h * 9) * 1024 + oc;
#pragma unroll
      for (int t = 0; t < 9; t++) {
        uint4 w0 = wbase[t * 1024];
        wr[t*4+0] = w0.x; wr[t*4+1] = w0.y; wr[t*4+2] = w0.z; wr[t*4+3] = w0.w;
      }
      int a0 = 0, a1 = 0;
      COL2(0,  1, 0, 0, 0, 0)
      COL2(1,  1, 1, 0, 0, 0)
      COL2(2,  1, 1, 1, 1, 0)
      COL2(3,  1, 1, 1, 1, 1)
      COL2(4,  1, 1, 1, 1, 2)
      COL2(5,  1, 1, 1, 1, 3)
      COL2(6,  1, 1, 1, 1, 4)
      COL2(7,  1, 1, 1, 1, 5)
      COL2(8,  1, 1, 1, 1, 6)
      COL2(9,  1, 1, 1, 1, 7)
      COL2(10, 1, 1, 1, 1, 8)
      COL2(11, 1, 1, 1, 1, 9)
      COL2(12, 1, 1, 1, 1, 10)
      COL2(13, 1, 1, 1, 1, 11)
      COL2(14, 0, 1, 1, 1, 12)
      COL2(15, 0, 0, 1, 1, 13)
    }
  }

  // bias + box-sum epilogue (hoisted out of the hot loop)
#pragma unroll 1
  for (int g2 = 0; g2 < 4; g2++) {
    const int oc2 = g2 * 256 + cchunk * 64 + lane;
    const float inv = bnA2[oc2], bb = bnB2[oc2];
#pragma unroll
    for (int xi = 0; xi < 14; xi++)
      val[xi] += fmaf(-inv, bsrow[ysub][s + xi][g2], bb);
  }

  const int c = cchunk * 64 + lane;
  const int obase = ((b * 256 + c) * 28 + y) * 28;
#pragma unroll
  for (int xi = 0; xi < 14; xi++) {
    int x = s + xi;
    float o = val[xi] + xin[obase + x];
    out[obase + x] = fmaxf(o, 0.0f);
  }
}

extern "C" void kernel_launch(void* const* d_in, const int* in_sizes, int n_in,
                              void* d_out, int out_size, void* d_ws, size_t ws_size,
                              hipStream_t stream) {
  const float* x   = (const float*)d_in[0];
  const float* w1  = (const float*)d_in[1];
  const float* s1  = (const float*)d_in[2];
  const float* b1  = (const float*)d_in[3];
  const float* m1  = (const float*)d_in[4];
  const float* v1  = (const float*)d_in[5];
  const float* w2  = (const float*)d_in[6];
  const float* s2  = (const float*)d_in[7];
  const float* b2  = (const float*)d_in[8];
  const float* m2  = (const float*)d_in[9];
  const float* v2  = (const float*)d_in[10];
  const float* lam = (const float*)d_in[11];
  float* out = (float*)d_out;

  char* ws = (char*)d_ws;
  uint*  A1p  = (uint*)(ws + 0);          //   802816 B
  uint*  W1p  = (uint*)(ws + 802816);     //   294912 B
  uint*  W2p  = (uint*)(ws + 1097728);    //   294912 B
  uint*  A2p  = (uint*)(ws + 1392640);    //  3211264 B
  float* bnA1 = (float*)(ws + 4603904);
  float* bnB1 = (float*)(ws + 4608000);
  float* bnA2 = (float*)(ws + 4612096);
  float* bnB2 = (float*)(ws + 4616192);

  kPrep<<<4, 256, 0, stream>>>(s1, b1, m1, v1, s2, b2, m2, v2, lam,
                               bnA1, bnB1, bnA2, bnB2);
  kPackX<<<1568, 256, 0, stream>>>(x, A1p);
  kPackW<<<9216, 256, 0, stream>>>(w1, W1p);
  kPackW<<<9216, 256, 0, stream>>>(w2, W2p);
  kConv1<<<dim3(4, 14, 32), 256, 0, stream>>>(A1p, W1p, bnA1, bnB1, A2p);
  kConv2<<<dim3(4, 14, 32), 256, 0, stream>>>(A2p, W2p, bnA2, bnB2, x, out);
}